// Round 5
// baseline (1007.921 us; speedup 1.0000x reference)
//
#include <hip/hip_runtime.h>
#include <math.h>

// CognitiveRouter: module routing (4) + grouped expert routing (16), combined
// hierarchical probs, top-4 + renorm.  T=32768, D=1536, fp32 in/out.
//
// R10 (R9 post-mortem: R5/R8/R9 all ~57us despite 3x different LDS-port
// loads -> LDS was never the pole. Zero-overlap accounting fits all three:
// HBM 32 + VALU ~19 (m07 103TF ceiling) + tails ~6 = 57. The per-iteration
// {burst loads -> compute -> vmcnt at register-rotate} convoys.)
// Changes vs R9:
//  1. hs staged via global_load_lds, DOUBLE-buffered wave-private, with
//     counted s_waitcnt vmcnt(2) -- never 0 in the loop (T4). Loads are
//     fire-and-forget: no VGPR target, nothing to convoy on; next window
//     stays in flight through current window's compute.
//  2. rows/lane=2 -> 4096 waves = 16 waves/CU (4/SIMD) for decorrelation.
//     __launch_bounds__(512,4) caps VGPR at 128 (acc=40, ~90 used, no
//     spill); LDS 40960 (weights, 3 stages of 8 j-windows) + 32768 (hs
//     dbuf) = 73728 B -> 2 blocks/CU.
//  3. Weight reads: R9's verified wl[jj][e][64] broadcast layout (16 slots
//     x 4-dup = 256B/read). hs reads: 64 distinct contiguous 16B slots,
//     conflict-free. Epilogue: R8's verified q<2 form. 3 restage barrier
//     pairs (weights 61KB don't fit with hs dbuf at 2 blocks/CU).

#define DD 1536
#define NM 4
#define NE 16
#define NW 20          // 16 expert rows + 4 module rows
#define NTHR 512
#define NWAVE 8
#define RPB 64         // 8 waves x 8 rows
#define NJ 24          // 64-col windows
#define SJ 8           // j-windows per weight stage
#define NSTAGE 3
#define WL_F (SJ * NW * 64)        // 10240 floats = 40960 B
#define HSB_F (NWAVE * 2 * 512)    // 8192 floats = 32768 B (2-deep dbuf/wave)

typedef float v4f __attribute__((ext_vector_type(4)));

__global__ __launch_bounds__(NTHR, 4)
void router_kernel(const float* __restrict__ hs,
                   const float* __restrict__ Wm,
                   const float* __restrict__ We,
                   float* __restrict__ out,
                   int T)
{
    __shared__ __align__(16) float wl[WL_F];    // staged weights (current 8 j)
    __shared__ __align__(16) float hsb[HSB_F];  // hs dbuf, wave-private slices
    const int tid  = threadIdx.x;
    const int wv   = tid >> 6;
    const int lane = tid & 63;
    const int q    = lane & 15;     // col slot within 64-col window
    const int g    = lane >> 4;     // row sub-group 0..3
    const int rW   = blockIdx.x * RPB + wv * 8;   // this wave's 8 rows

    // DMA source: instr i deposits lane l's 16B at LDS l*16; lane l must
    // supply src row rW + i*4 + (l>>4), col j*64 + (l&15)*4.
    const float* dmaBase = hs + (size_t)(rW + g) * DD + q * 4;
    const int hsbOff = __builtin_amdgcn_readfirstlane(wv * 1024);

    float accA[NW], accB[NW];
#pragma unroll
    for (int e = 0; e < NW; e++) { accA[e] = 0.f; accB[e] = 0.f; }

    // ---- issue DMA for j=0 into buf0 (completes under weight staging) ----
    {
        float* d0 = &hsb[hsbOff];
        __builtin_amdgcn_global_load_lds(
            (const __attribute__((address_space(1))) void*)(dmaBase),
            (__attribute__((address_space(3))) void*)d0, 16, 0, 0);
        __builtin_amdgcn_global_load_lds(
            (const __attribute__((address_space(1))) void*)(dmaBase + 4 * DD),
            (__attribute__((address_space(3))) void*)(d0 + 256), 16, 0, 0);
    }

    // ---- weight stage 0: wl[jw][e][qc], 512 thr x 5 v4f = 10240 floats ----
#pragma unroll
    for (int it = 0; it < 5; it++) {
        const int off = tid * 4 + it * 2048;
        const int jw  = off / 1280;
        const int rem = off - jw * 1280;
        const int e   = rem >> 6;
        const int qc  = rem & 63;
        const int col = jw * 64 + qc;          // stage 0: global j == jw
        v4f w = (e < NE) ? *(const v4f*)(We + (size_t)e * DD + col)
                         : *(const v4f*)(Wm + (size_t)(e - NE) * DD + col);
        *(v4f*)&wl[off] = w;
    }
    __syncthreads();   // weights visible; also drains j=0 DMA (vmcnt 0)

#pragma unroll 1
    for (int s = 0; s < NSTAGE; s++) {
        if (s) {
            __syncthreads();     // all waves done reading previous wl stage
#pragma unroll
            for (int it = 0; it < 5; it++) {
                const int off = tid * 4 + it * 2048;
                const int jw  = off / 1280;
                const int rem = off - jw * 1280;
                const int e   = rem >> 6;
                const int qc  = rem & 63;
                const int col = (s * SJ + jw) * 64 + qc;
                v4f w = (e < NE) ? *(const v4f*)(We + (size_t)e * DD + col)
                                 : *(const v4f*)(Wm + (size_t)(e - NE) * DD + col);
                *(v4f*)&wl[off] = w;
            }
            __syncthreads();
        }
#pragma unroll
        for (int jj = 0; jj < SJ; jj++) {
            const int j   = s * SJ + jj;
            const int cur = j & 1;
            if (j + 1 < NJ) {
                // issue next window into the other buffer, keep it in flight
                float* dn = &hsb[hsbOff + (cur ^ 1) * 512];
                const float* sn = dmaBase + (j + 1) * 64;
                __builtin_amdgcn_global_load_lds(
                    (const __attribute__((address_space(1))) void*)sn,
                    (__attribute__((address_space(3))) void*)dn, 16, 0, 0);
                __builtin_amdgcn_global_load_lds(
                    (const __attribute__((address_space(1))) void*)(sn + 4 * DD),
                    (__attribute__((address_space(3))) void*)(dn + 256), 16, 0, 0);
                asm volatile("s_waitcnt vmcnt(2)" ::: "memory");  // prev done, cur 2 in flight
            } else {
                asm volatile("s_waitcnt vmcnt(0)" ::: "memory");  // last window
            }
            // hs reads: 64 distinct contiguous 16B slots, conflict-free
            v4f h0 = *(const v4f*)&hsb[hsbOff + cur * 512 + g * 64 + q * 4];
            v4f h1 = *(const v4f*)&hsb[hsbOff + cur * 512 + 256 + g * 64 + q * 4];
            const float* wb = &wl[jj * 1280 + q * 4];
#pragma unroll
            for (int e = 0; e < NW; e++) {
                v4f w = *(const v4f*)(wb + e * 64);   // 256B broadcast read
                accA[e] = fmaf(h0.x, w.x, accA[e]); accA[e] = fmaf(h0.y, w.y, accA[e]);
                accA[e] = fmaf(h0.z, w.z, accA[e]); accA[e] = fmaf(h0.w, w.w, accA[e]);
                accB[e] = fmaf(h1.x, w.x, accB[e]); accB[e] = fmaf(h1.y, w.y, accB[e]);
                accB[e] = fmaf(h1.z, w.z, accB[e]); accB[e] = fmaf(h1.w, w.w, accB[e]);
            }
        }
    }

    // ---- in-register split-col reduction over the 16 q-lanes ----
#pragma unroll
    for (int e = 0; e < NW; e++) {
        accA[e] += __shfl_xor(accA[e], 1); accA[e] += __shfl_xor(accA[e], 2);
        accA[e] += __shfl_xor(accA[e], 4); accA[e] += __shfl_xor(accA[e], 8);
        accB[e] += __shfl_xor(accB[e], 1); accB[e] += __shfl_xor(accB[e], 2);
        accB[e] += __shfl_xor(accB[e], 4); accB[e] += __shfl_xor(accB[e], 8);
    }

    // ---- epilogue (R8-verified): q==0 -> row rW+g, q==1 -> row rW+g+4 ----
    if (q < 2) {
        float logit[NW];
#pragma unroll
        for (int e = 0; e < NW; e++) logit[e] = q ? accB[e] : accA[e];
        const int row = rW + g + (q ? 4 : 0);

        // module softmax over logit[16..19]
        float mmax = logit[16];
#pragma unroll
        for (int m = 1; m < NM; m++) mmax = fmaxf(mmax, logit[16 + m]);
        float mexp[NM], msum = 0.f;
#pragma unroll
        for (int m = 0; m < NM; m++) { mexp[m] = expf(logit[16 + m] - mmax); msum += mexp[m]; }

        // per-module expert softmax, combined probs
        float comb[NE];
#pragma unroll
        for (int m = 0; m < NM; m++) {
            float mprob = mexp[m] / msum;
            float emax = logit[m * 4];
#pragma unroll
            for (int jj = 1; jj < 4; jj++) emax = fmaxf(emax, logit[m * 4 + jj]);
            float ee[4], esum = 0.f;
#pragma unroll
            for (int jj = 0; jj < 4; jj++) { ee[jj] = expf(logit[m * 4 + jj] - emax); esum += ee[jj]; }
            float scale = mprob / esum;
#pragma unroll
            for (int jj = 0; jj < 4; jj++) comb[m * 4 + jj] = ee[jj] * scale;
        }

        float4* cw = (float4*)(out + (size_t)row * 16);
        cw[0] = make_float4(comb[0],  comb[1],  comb[2],  comb[3]);
        cw[1] = make_float4(comb[4],  comb[5],  comb[6],  comb[7]);
        cw[2] = make_float4(comb[8],  comb[9],  comb[10], comb[11]);
        cw[3] = make_float4(comb[12], comb[13], comb[14], comb[15]);

        // top-4, descending, strict > so lowest index wins ties (lax.top_k)
        float tv[4]; int ti[4];
        unsigned mask = 0;
#pragma unroll
        for (int k = 0; k < 4; k++) {
            float best = -1.f; int bi = 0;
#pragma unroll
            for (int i = 0; i < NE; i++) {
                bool avail = !((mask >> i) & 1u);
                if (avail && comb[i] > best) { best = comb[i]; bi = i; }
            }
            tv[k] = best; ti[k] = bi; mask |= 1u << bi;
        }
        float s = tv[0] + tv[1] + tv[2] + tv[3] + 1e-8f;

        const size_t wOff = (size_t)T * 16;          // top_k_weights region
        const size_t iOff = (size_t)T * 20;          // top_k_indices region
        float4* ww = (float4*)(out + wOff + (size_t)row * 4);
        *ww = make_float4(tv[0] / s, tv[1] / s, tv[2] / s, tv[3] / s);
        float4* iw = (float4*)(out + iOff + (size_t)row * 4);
        *iw = make_float4((float)ti[0], (float)ti[1], (float)ti[2], (float)ti[3]);
    }
}

extern "C" void kernel_launch(void* const* d_in, const int* in_sizes, int n_in,
                              void* d_out, int out_size, void* d_ws, size_t ws_size,
                              hipStream_t stream)
{
    const float* hs = (const float*)d_in[0];   // (T, 1536)
    const float* Wm = (const float*)d_in[1];   // (4, 1536)
    const float* We = (const float*)d_in[2];   // (16, 1536)
    float* out = (float*)d_out;
    const int T = in_sizes[0] / DD;            // 32768
    router_kernel<<<T / RPB, NTHR, 0, stream>>>(hs, Wm, We, out, T);
}

// Round 6
// 884.469 us; speedup vs baseline: 1.1396x; 1.1396x over previous
//
#include <hip/hip_runtime.h>
#include <math.h>

// CognitiveRouter: module routing (4) + grouped expert routing (16), combined
// hierarchical probs, top-4 + renorm.  T=32768, D=1536, fp32 in/out.
//
// R11 (R10 post-mortem: 822us, VGPR_Count=64 == the cap implied by my own
// __launch_bounds__(512,4). RA spilled the 40 accumulators: WRITE 1.69GB,
// FETCH 950MB (201 hs + ~700 scratch re-reads), VALUBusy 4.2%. The
// DMA-dbuf + counted-vmcnt mechanism never got a fair test.)
// Changes vs R10 (single-variable: release the clamp):
//  1. __launch_bounds__(512, 2): VGPR cap 128 (~90 live, no spill).
//     Occupancy is LDS-capped at 2 blocks/CU = 16 waves/CU anyway.
//  2. s_waitcnt lgkmcnt(0) before each DMA issue: closes the theoretical
//     ds_read-vs-DMA-overwrite race on the recycled buffer (costs ~nothing,
//     the FMAs already force those lgkm waits).
// Keep from R10: hs via global_load_lds, wave-private 2-deep dbuf, counted
// s_waitcnt vmcnt(2) in-loop (never 0 except last window); weights staged
// in 3 chunks of 8 j-windows (40KB) + hs dbuf (32KB) = 73.7KB -> 2 blk/CU;
// wl[jj][e][64] broadcast layout; __shfl_xor reduce; R8-verified epilogue.

#define DD 1536
#define NM 4
#define NE 16
#define NW 20          // 16 expert rows + 4 module rows
#define NTHR 512
#define NWAVE 8
#define RPB 64         // 8 waves x 8 rows
#define NJ 24          // 64-col windows
#define SJ 8           // j-windows per weight stage
#define NSTAGE 3
#define WL_F (SJ * NW * 64)        // 10240 floats = 40960 B
#define HSB_F (NWAVE * 2 * 512)    // 8192 floats = 32768 B (2-deep dbuf/wave)

typedef float v4f __attribute__((ext_vector_type(4)));

__global__ __launch_bounds__(NTHR, 2)
void router_kernel(const float* __restrict__ hs,
                   const float* __restrict__ Wm,
                   const float* __restrict__ We,
                   float* __restrict__ out,
                   int T)
{
    __shared__ __align__(16) float wl[WL_F];    // staged weights (current 8 j)
    __shared__ __align__(16) float hsb[HSB_F];  // hs dbuf, wave-private slices
    const int tid  = threadIdx.x;
    const int wv   = tid >> 6;
    const int lane = tid & 63;
    const int q    = lane & 15;     // col slot within 64-col window
    const int g    = lane >> 4;     // row sub-group 0..3
    const int rW   = blockIdx.x * RPB + wv * 8;   // this wave's 8 rows

    // DMA source: instr i deposits lane l's 16B at LDS base + l*16; lane l
    // supplies src row rW + i*4 + (l>>4), col j*64 + (l&15)*4.
    const float* dmaBase = hs + (size_t)(rW + g) * DD + q * 4;
    const int hsbOff = __builtin_amdgcn_readfirstlane(wv * 1024);

    float accA[NW], accB[NW];
#pragma unroll
    for (int e = 0; e < NW; e++) { accA[e] = 0.f; accB[e] = 0.f; }

    // ---- issue DMA for j=0 into buf0 (completes under weight staging) ----
    {
        float* d0 = &hsb[hsbOff];
        __builtin_amdgcn_global_load_lds(
            (const __attribute__((address_space(1))) void*)(dmaBase),
            (__attribute__((address_space(3))) void*)d0, 16, 0, 0);
        __builtin_amdgcn_global_load_lds(
            (const __attribute__((address_space(1))) void*)(dmaBase + 4 * DD),
            (__attribute__((address_space(3))) void*)(d0 + 256), 16, 0, 0);
    }

    // ---- weight stage 0: wl[jw][e][qc], 512 thr x 5 v4f = 10240 floats ----
#pragma unroll
    for (int it = 0; it < 5; it++) {
        const int off = tid * 4 + it * 2048;
        const int jw  = off / 1280;
        const int rem = off - jw * 1280;
        const int e   = rem >> 6;
        const int qc  = rem & 63;
        const int col = jw * 64 + qc;          // stage 0: global j == jw
        v4f w = (e < NE) ? *(const v4f*)(We + (size_t)e * DD + col)
                         : *(const v4f*)(Wm + (size_t)(e - NE) * DD + col);
        *(v4f*)&wl[off] = w;
    }
    __syncthreads();   // weights visible; also drains j=0 DMA (vmcnt 0)

#pragma unroll 1
    for (int s = 0; s < NSTAGE; s++) {
        if (s) {
            __syncthreads();     // all waves done reading previous wl stage
#pragma unroll
            for (int it = 0; it < 5; it++) {
                const int off = tid * 4 + it * 2048;
                const int jw  = off / 1280;
                const int rem = off - jw * 1280;
                const int e   = rem >> 6;
                const int qc  = rem & 63;
                const int col = (s * SJ + jw) * 64 + qc;
                v4f w = (e < NE) ? *(const v4f*)(We + (size_t)e * DD + col)
                                 : *(const v4f*)(Wm + (size_t)(e - NE) * DD + col);
                *(v4f*)&wl[off] = w;
            }
            __syncthreads();
        }
#pragma unroll
        for (int jj = 0; jj < SJ; jj++) {
            const int j   = s * SJ + jj;
            const int cur = j & 1;
            if (j + 1 < NJ) {
                // prev window's ds_reads must be complete before this DMA
                // may overwrite the buffer it targets (cheap: FMAs already
                // forced most of these waits).
                asm volatile("s_waitcnt lgkmcnt(0)" ::: "memory");
                // issue next window into the other buffer, keep it in flight
                float* dn = &hsb[hsbOff + (cur ^ 1) * 512];
                const float* sn = dmaBase + (j + 1) * 64;
                __builtin_amdgcn_global_load_lds(
                    (const __attribute__((address_space(1))) void*)sn,
                    (__attribute__((address_space(3))) void*)dn, 16, 0, 0);
                __builtin_amdgcn_global_load_lds(
                    (const __attribute__((address_space(1))) void*)(sn + 4 * DD),
                    (__attribute__((address_space(3))) void*)(dn + 256), 16, 0, 0);
                asm volatile("s_waitcnt vmcnt(2)" ::: "memory");  // prev done, cur 2 in flight
            } else {
                asm volatile("s_waitcnt vmcnt(0)" ::: "memory");  // last window
            }
            // hs reads: 64 distinct contiguous 16B slots, conflict-free
            v4f h0 = *(const v4f*)&hsb[hsbOff + cur * 512 + g * 64 + q * 4];
            v4f h1 = *(const v4f*)&hsb[hsbOff + cur * 512 + 256 + g * 64 + q * 4];
            const float* wb = &wl[jj * 1280 + q * 4];
#pragma unroll
            for (int e = 0; e < NW; e++) {
                v4f w = *(const v4f*)(wb + e * 64);   // 256B broadcast read
                accA[e] = fmaf(h0.x, w.x, accA[e]); accA[e] = fmaf(h0.y, w.y, accA[e]);
                accA[e] = fmaf(h0.z, w.z, accA[e]); accA[e] = fmaf(h0.w, w.w, accA[e]);
                accB[e] = fmaf(h1.x, w.x, accB[e]); accB[e] = fmaf(h1.y, w.y, accB[e]);
                accB[e] = fmaf(h1.z, w.z, accB[e]); accB[e] = fmaf(h1.w, w.w, accB[e]);
            }
        }
    }

    // ---- in-register split-col reduction over the 16 q-lanes ----
#pragma unroll
    for (int e = 0; e < NW; e++) {
        accA[e] += __shfl_xor(accA[e], 1); accA[e] += __shfl_xor(accA[e], 2);
        accA[e] += __shfl_xor(accA[e], 4); accA[e] += __shfl_xor(accA[e], 8);
        accB[e] += __shfl_xor(accB[e], 1); accB[e] += __shfl_xor(accB[e], 2);
        accB[e] += __shfl_xor(accB[e], 4); accB[e] += __shfl_xor(accB[e], 8);
    }

    // ---- epilogue (R8-verified): q==0 -> row rW+g, q==1 -> row rW+g+4 ----
    if (q < 2) {
        float logit[NW];
#pragma unroll
        for (int e = 0; e < NW; e++) logit[e] = q ? accB[e] : accA[e];
        const int row = rW + g + (q ? 4 : 0);

        // module softmax over logit[16..19]
        float mmax = logit[16];
#pragma unroll
        for (int m = 1; m < NM; m++) mmax = fmaxf(mmax, logit[16 + m]);
        float mexp[NM], msum = 0.f;
#pragma unroll
        for (int m = 0; m < NM; m++) { mexp[m] = expf(logit[16 + m] - mmax); msum += mexp[m]; }

        // per-module expert softmax, combined probs
        float comb[NE];
#pragma unroll
        for (int m = 0; m < NM; m++) {
            float mprob = mexp[m] / msum;
            float emax = logit[m * 4];
#pragma unroll
            for (int jj = 1; jj < 4; jj++) emax = fmaxf(emax, logit[m * 4 + jj]);
            float ee[4], esum = 0.f;
#pragma unroll
            for (int jj = 0; jj < 4; jj++) { ee[jj] = expf(logit[m * 4 + jj] - emax); esum += ee[jj]; }
            float scale = mprob / esum;
#pragma unroll
            for (int jj = 0; jj < 4; jj++) comb[m * 4 + jj] = ee[jj] * scale;
        }

        float4* cw = (float4*)(out + (size_t)row * 16);
        cw[0] = make_float4(comb[0],  comb[1],  comb[2],  comb[3]);
        cw[1] = make_float4(comb[4],  comb[5],  comb[6],  comb[7]);
        cw[2] = make_float4(comb[8],  comb[9],  comb[10], comb[11]);
        cw[3] = make_float4(comb[12], comb[13], comb[14], comb[15]);

        // top-4, descending, strict > so lowest index wins ties (lax.top_k)
        float tv[4]; int ti[4];
        unsigned mask = 0;
#pragma unroll
        for (int k = 0; k < 4; k++) {
            float best = -1.f; int bi = 0;
#pragma unroll
            for (int i = 0; i < NE; i++) {
                bool avail = !((mask >> i) & 1u);
                if (avail && comb[i] > best) { best = comb[i]; bi = i; }
            }
            tv[k] = best; ti[k] = bi; mask |= 1u << bi;
        }
        float s = tv[0] + tv[1] + tv[2] + tv[3] + 1e-8f;

        const size_t wOff = (size_t)T * 16;          // top_k_weights region
        const size_t iOff = (size_t)T * 20;          // top_k_indices region
        float4* ww = (float4*)(out + wOff + (size_t)row * 4);
        *ww = make_float4(tv[0] / s, tv[1] / s, tv[2] / s, tv[3] / s);
        float4* iw = (float4*)(out + iOff + (size_t)row * 4);
        *iw = make_float4((float)ti[0], (float)ti[1], (float)ti[2], (float)ti[3]);
    }
}

extern "C" void kernel_launch(void* const* d_in, const int* in_sizes, int n_in,
                              void* d_out, int out_size, void* d_ws, size_t ws_size,
                              hipStream_t stream)
{
    const float* hs = (const float*)d_in[0];   // (T, 1536)
    const float* Wm = (const float*)d_in[1];   // (4, 1536)
    const float* We = (const float*)d_in[2];   // (16, 1536)
    float* out = (float*)d_out;
    const int T = in_sizes[0] / DD;            // 32768
    router_kernel<<<T / RPB, NTHR, 0, stream>>>(hs, Wm, We, out, T);
}

// Round 7
// 294.363 us; speedup vs baseline: 3.4241x; 3.0047x over previous
//
#include <hip/hip_runtime.h>
#include <math.h>

// CognitiveRouter: module routing (4) + grouped expert routing (16), combined
// hierarchical probs, top-4 + renorm.  T=32768, D=1536, fp32 in/out.
//
// R12 (R11 post-mortem: VGPR_Count=128 == cap again, WRITE 1.27GB -- the
// compiler pipelines the 20 weight ds_reads (hoists ~20x4 regs) so the loop
// needs ~140-180 VGPRs; ANY cap <=128 spills. Structural conclusion: this
// schedule requires the uncapped 256-VGPR budget => 1 block/CU, 8 waves.)
// R12 = R9's exact spill-free shape (4 rows/lane, 80 acc, 512 thr, 1 blk/CU,
// no min-waves clamp, verified epilogue) with ONLY the hs path changed:
//  1. hs via fire-and-forget global_load_lds into a wave-private 3-deep
//     LDS ring (4KB/window: 16 rows x 64 cols). Counted s_waitcnt vmcnt(8)
//     in steady state (2 windows always in flight) -- never 0 except the
//     per-stage tail. Nothing for the wave to convoy on: no VGPR load
//     targets, no register-rotate.
//  2. Weights in 3 stages of 8 j-windows (R10-verified staging map, 40KB)
//     since wl-full (122.8KB) + ring (96KB) doesn't fit. 2 restage barrier
//     pairs; barriers drain DMA (compiler vmcnt(0) before s_barrier) --
//     that's 2 bubbles, accepted.
//  3. lgkmcnt(0) before each DMA issue (buffer-recycle safety, ~free).
// This is the clean A/B of the convoy theory at proven-spill-free pressure:
// R9 (VGPR rotate) = 57us vs R12 (decoupled DMA), same occupancy.

#define DD 1536
#define NM 4
#define NE 16
#define NW 20          // 16 expert rows + 4 module rows
#define NTHR 512
#define NWAVE 8
#define RPB 128        // 8 waves x 16 rows
#define NJ 24          // 64-col windows
#define SJ 8           // j-windows per weight stage
#define NSTAGE 3
#define WL_F (SJ * NW * 64)         // 10240 floats = 40960 B
#define RING_F (NWAVE * 3 * 1024)   // 24576 floats = 98304 B (3-deep ring/wave)

typedef float v4f __attribute__((ext_vector_type(4)));

__global__ __launch_bounds__(NTHR)
void router_kernel(const float* __restrict__ hs,
                   const float* __restrict__ Wm,
                   const float* __restrict__ We,
                   float* __restrict__ out,
                   int T)
{
    __shared__ __align__(16) float wl[WL_F];     // staged weights (current 8 j)
    __shared__ __align__(16) float hsb[RING_F];  // hs ring, wave-private slices
    const int tid  = threadIdx.x;
    const int wv   = tid >> 6;
    const int lane = tid & 63;
    const int q    = lane & 15;     // col slot within 64-col window
    const int g    = lane >> 4;     // row sub-group 0..3
    const int rW   = blockIdx.x * RPB + wv * 16;  // this wave's 16 rows

    // DMA: instr i of window j deposits lane l's 16B at ring + i*1024 + l*16;
    // lane l supplies src row rW + i*4 + (l>>4), col j*64 + (l&15)*4.
    // Read-back: h_i for lane (q,g) at ring + i*256 + g*64 + q*4 (row rW+4i+g).
    const float* dmaBase = hs + (size_t)(rW + g) * DD + q * 4;
    const int ringOff = __builtin_amdgcn_readfirstlane(wv * 3072);

    float accA[NW], accB[NW], accC[NW], accD[NW];
#pragma unroll
    for (int e = 0; e < NW; e++) { accA[e] = 0.f; accB[e] = 0.f; accC[e] = 0.f; accD[e] = 0.f; }

    // ---- issue windows 0,1 (land under weight staging / barrier drain) ----
#pragma unroll
    for (int w2 = 0; w2 < 2; w2++) {
        float* d = &hsb[ringOff + w2 * 1024];
        const float* s0 = dmaBase + (size_t)w2 * 64;
#pragma unroll
        for (int i = 0; i < 4; i++)
            __builtin_amdgcn_global_load_lds(
                (const __attribute__((address_space(1))) void*)(s0 + (size_t)(i * 4) * DD),
                (__attribute__((address_space(3))) void*)(d + i * 256), 16, 0, 0);
    }

    // ---- weight stage 0: wl[jw][e][qc] (R10-verified map) ----
#pragma unroll
    for (int it = 0; it < 5; it++) {
        const int off = tid * 4 + it * 2048;
        const int jw  = off / 1280;
        const int rem = off - jw * 1280;
        const int e   = rem >> 6;
        const int qc  = rem & 63;
        const int col = jw * 64 + qc;
        v4f w = (e < NE) ? *(const v4f*)(We + (size_t)e * DD + col)
                         : *(const v4f*)(Wm + (size_t)(e - NE) * DD + col);
        *(v4f*)&wl[off] = w;
    }
    __syncthreads();   // weights visible; drains windows 0,1 (data lands, stays valid)

#pragma unroll 1
    for (int s = 0; s < NSTAGE; s++) {
        if (s) {
            __syncthreads();     // all waves done reading previous wl stage
            // issue this stage's windows 0,1 (land under the restage barrier)
#pragma unroll
            for (int w2 = 0; w2 < 2; w2++) {
                float* d = &hsb[ringOff + w2 * 1024];
                const float* s0 = dmaBase + (size_t)(s * SJ + w2) * 64;
#pragma unroll
                for (int i = 0; i < 4; i++)
                    __builtin_amdgcn_global_load_lds(
                        (const __attribute__((address_space(1))) void*)(s0 + (size_t)(i * 4) * DD),
                        (__attribute__((address_space(3))) void*)(d + i * 256), 16, 0, 0);
            }
#pragma unroll
            for (int it = 0; it < 5; it++) {
                const int off = tid * 4 + it * 2048;
                const int jw  = off / 1280;
                const int rem = off - jw * 1280;
                const int e   = rem >> 6;
                const int qc  = rem & 63;
                const int col = (s * SJ + jw) * 64 + qc;
                v4f w = (e < NE) ? *(const v4f*)(We + (size_t)e * DD + col)
                                 : *(const v4f*)(Wm + (size_t)(e - NE) * DD + col);
                *(v4f*)&wl[off] = w;
            }
            __syncthreads();
        }
#pragma unroll 1
        for (int jj = 0; jj < SJ; jj++) {
            if (jj + 2 < SJ) {
                // buffer-recycle safety: prior reads of the target buffer
                // must be complete (cheap: FMAs already forced those waits)
                asm volatile("s_waitcnt lgkmcnt(0)" ::: "memory");
                const int buf = (jj + 2) % 3;
                float* d = &hsb[ringOff + buf * 1024];
                const float* s0 = dmaBase + (size_t)(s * SJ + jj + 2) * 64;
#pragma unroll
                for (int i = 0; i < 4; i++)
                    __builtin_amdgcn_global_load_lds(
                        (const __attribute__((address_space(1))) void*)(s0 + (size_t)(i * 4) * DD),
                        (__attribute__((address_space(3))) void*)(d + i * 256), 16, 0, 0);
                asm volatile("s_waitcnt vmcnt(8)" ::: "memory");   // window jj done; 2 in flight
            } else if (jj == SJ - 2) {
                asm volatile("s_waitcnt vmcnt(4)" ::: "memory");
            } else {
                asm volatile("s_waitcnt vmcnt(0)" ::: "memory");
            }
            const float* hb = &hsb[ringOff + (jj % 3) * 1024 + g * 64 + q * 4];
            v4f h0 = *(const v4f*)(hb);
            v4f h1 = *(const v4f*)(hb + 256);
            v4f h2 = *(const v4f*)(hb + 512);
            v4f h3 = *(const v4f*)(hb + 768);
            const float* wb = &wl[jj * 1280 + q * 4];
#pragma unroll
            for (int e = 0; e < NW; e++) {
                v4f w = *(const v4f*)(wb + e * 64);   // 256B broadcast read
                accA[e] = fmaf(h0.x, w.x, accA[e]); accA[e] = fmaf(h0.y, w.y, accA[e]);
                accA[e] = fmaf(h0.z, w.z, accA[e]); accA[e] = fmaf(h0.w, w.w, accA[e]);
                accB[e] = fmaf(h1.x, w.x, accB[e]); accB[e] = fmaf(h1.y, w.y, accB[e]);
                accB[e] = fmaf(h1.z, w.z, accB[e]); accB[e] = fmaf(h1.w, w.w, accB[e]);
                accC[e] = fmaf(h2.x, w.x, accC[e]); accC[e] = fmaf(h2.y, w.y, accC[e]);
                accC[e] = fmaf(h2.z, w.z, accC[e]); accC[e] = fmaf(h2.w, w.w, accC[e]);
                accD[e] = fmaf(h3.x, w.x, accD[e]); accD[e] = fmaf(h3.y, w.y, accD[e]);
                accD[e] = fmaf(h3.z, w.z, accD[e]); accD[e] = fmaf(h3.w, w.w, accD[e]);
            }
        }
    }

    // ---- in-register split-col reduction over the 16 q-lanes ----
#pragma unroll
    for (int e = 0; e < NW; e++) {
        accA[e] += __shfl_xor(accA[e], 1); accA[e] += __shfl_xor(accA[e], 2);
        accA[e] += __shfl_xor(accA[e], 4); accA[e] += __shfl_xor(accA[e], 8);
        accB[e] += __shfl_xor(accB[e], 1); accB[e] += __shfl_xor(accB[e], 2);
        accB[e] += __shfl_xor(accB[e], 4); accB[e] += __shfl_xor(accB[e], 8);
        accC[e] += __shfl_xor(accC[e], 1); accC[e] += __shfl_xor(accC[e], 2);
        accC[e] += __shfl_xor(accC[e], 4); accC[e] += __shfl_xor(accC[e], 8);
        accD[e] += __shfl_xor(accD[e], 1); accD[e] += __shfl_xor(accD[e], 2);
        accD[e] += __shfl_xor(accD[e], 4); accD[e] += __shfl_xor(accD[e], 8);
    }

    // ---- epilogue (R9-verified): q==0..3 -> rows rW + g + 4q ----
    if (q < 4) {
        float logit[NW];
#pragma unroll
        for (int e = 0; e < NW; e++)
            logit[e] = (q == 0) ? accA[e] : (q == 1) ? accB[e]
                     : (q == 2) ? accC[e] : accD[e];
        const int row = rW + g + q * 4;

        // module softmax over logit[16..19]
        float mmax = logit[16];
#pragma unroll
        for (int m = 1; m < NM; m++) mmax = fmaxf(mmax, logit[16 + m]);
        float mexp[NM], msum = 0.f;
#pragma unroll
        for (int m = 0; m < NM; m++) { mexp[m] = expf(logit[16 + m] - mmax); msum += mexp[m]; }

        // per-module expert softmax, combined probs
        float comb[NE];
#pragma unroll
        for (int m = 0; m < NM; m++) {
            float mprob = mexp[m] / msum;
            float emax = logit[m * 4];
#pragma unroll
            for (int jj = 1; jj < 4; jj++) emax = fmaxf(emax, logit[m * 4 + jj]);
            float ee[4], esum = 0.f;
#pragma unroll
            for (int jj = 0; jj < 4; jj++) { ee[jj] = expf(logit[m * 4 + jj] - emax); esum += ee[jj]; }
            float scale = mprob / esum;
#pragma unroll
            for (int jj = 0; jj < 4; jj++) comb[m * 4 + jj] = ee[jj] * scale;
        }

        float4* cw = (float4*)(out + (size_t)row * 16);
        cw[0] = make_float4(comb[0],  comb[1],  comb[2],  comb[3]);
        cw[1] = make_float4(comb[4],  comb[5],  comb[6],  comb[7]);
        cw[2] = make_float4(comb[8],  comb[9],  comb[10], comb[11]);
        cw[3] = make_float4(comb[12], comb[13], comb[14], comb[15]);

        // top-4, descending, strict > so lowest index wins ties (lax.top_k)
        float tv[4]; int ti[4];
        unsigned mask = 0;
#pragma unroll
        for (int k = 0; k < 4; k++) {
            float best = -1.f; int bi = 0;
#pragma unroll
            for (int i = 0; i < NE; i++) {
                bool avail = !((mask >> i) & 1u);
                if (avail && comb[i] > best) { best = comb[i]; bi = i; }
            }
            tv[k] = best; ti[k] = bi; mask |= 1u << bi;
        }
        float s = tv[0] + tv[1] + tv[2] + tv[3] + 1e-8f;

        const size_t wOff = (size_t)T * 16;          // top_k_weights region
        const size_t iOff = (size_t)T * 20;          // top_k_indices region
        float4* ww = (float4*)(out + wOff + (size_t)row * 4);
        *ww = make_float4(tv[0] / s, tv[1] / s, tv[2] / s, tv[3] / s);
        float4* iw = (float4*)(out + iOff + (size_t)row * 4);
        *iw = make_float4((float)ti[0], (float)ti[1], (float)ti[2], (float)ti[3]);
    }
}

extern "C" void kernel_launch(void* const* d_in, const int* in_sizes, int n_in,
                              void* d_out, int out_size, void* d_ws, size_t ws_size,
                              hipStream_t stream)
{
    const float* hs = (const float*)d_in[0];   // (T, 1536)
    const float* Wm = (const float*)d_in[1];   // (4, 1536)
    const float* We = (const float*)d_in[2];   // (16, 1536)
    float* out = (float*)d_out;
    const int T = in_sizes[0] / DD;            // 32768
    router_kernel<<<T / RPB, NTHR, 0, stream>>>(hs, Wm, We, out, T);
}